// Round 7
// baseline (812.404 us; speedup 1.0000x reference)
//
#include <hip/hip_runtime.h>
#include <math.h>

#define SS 1024
#define DD 64
#define BH 64

typedef __attribute__((ext_vector_type(4))) float fx4;
typedef __attribute__((ext_vector_type(8))) short sx8;
typedef __attribute__((ext_vector_type(4))) short sx4;

__device__ __forceinline__ unsigned short f2bf(float x) {
  unsigned u = __builtin_bit_cast(unsigned, x);
  u += 0x7fffu + ((u >> 16) & 1u);
  return (unsigned short)(u >> 16);
}
__device__ __forceinline__ float bf2f(unsigned short h) {
  return __builtin_bit_cast(float, ((unsigned)h) << 16);
}

// ---------------------------------------------------------------------------
// Fully-fused kernel (single launch, no workspace). VERIFIED round-6 control
// flow: __syncthreads at every phase boundary, identical LDS aliasing,
// identical arithmetic. Round-7 changes (latency-hiding only):
//  1) UNPAIRED stripes: 1024 blocks, one 64-row stripe each. LDS 54272*3 =
//     162816 <= 163840 -> 3 blocks/CU = 12 waves (was 8), and co-resident
//     blocks sit at different stripe depths (no cross-block lockstep).
//     Heavy stripes (it=15) dispatch FIRST per XCD; light stripes (which
//     also carry the bigger W-zero job) backfill the tail.
//  2) K/RK register prefetch one tile ahead (12 float4 = 48 VGPR): issued
//     at phase-2 start under the logits MFMAs, consumed in the next tile's
//     phase 1. Wave-private regs; every __syncthreads in between drains
//     vmcnt anyway, so the loads are complete (and free) at consumption.
// ---------------------------------------------------------------------------
__global__ __launch_bounds__(256, 3) void k_fused(
    const float* __restrict__ q, const float* __restrict__ k,
    const float* __restrict__ v, const float* __restrict__ RK,
    const float* __restrict__ RV, float* __restrict__ W, float* __restrict__ O) {
  // bid -> (xcd, it, bh): XCD x owns bh in [8x,8x+8) (L2 locality, as before);
  // within each XCD, stripes dispatch heavy-first (it = 15,14,...,0).
  const int bid = (blockIdx.y << 4) | blockIdx.x;  // 1024 blocks
  const int xcd = bid & 7, rest = bid >> 3;
  const int it = 15 - (rest & 15);
  const int bh = (xcd << 3) | (rest >> 4);
  const int i0 = it << 6;

  __shared__ __align__(16) char smem[54272];
  short* const sKh = (short*)smem;            // [64*72]
  short* const sKl = (short*)(smem + 9216);   // [64*72]
  short* const sRh = (short*)(smem + 18432);  // [128*72]          ends 36864
  short* const vT  = (short*)smem;            // [64*74]  (aliases sKh..)
  short* const rvT = (short*)(smem + 9472);   // [64*138] (aliases sKl/sRh)
  short* const wA  = (short*)(smem + 27136);  // [64*72]  ends 36352
  short* const wSk = (short*)(smem + 36864);  // [64*136] exclusive, ends 54272
  float* const rowInvLds = (float*)(smem + 27136);  // [64] tail-only (reuses wA)

  const int t = threadIdx.x;
  const int lane = t & 63, mt = t >> 6, quad = lane >> 4, lc = lane & 15;

  // one-time: zero the never-valid wSk slots (wave-private rows; no barrier)
#pragma unroll
  for (int e = 0; e < 4; ++e) {
    const int rr = quad * 4 + e;
    const int rloc = mt * 16 + rr;
    const int du = 63 + lc - rr;         // [48,78]
    const int us0 = du & 15;
    const int A = (du >> 4) - mt;        // valid kk = nt + A, nt=0..3
#pragma unroll
    for (int kk = 0; kk < 8; ++kk) {
      if (kk < A || kk > A + 3) wSk[rloc * 136 + us0 + 16 * kk] = 0;
    }
  }

  // ---- K/RK one-tile-ahead register prefetch (wave-private) ---------------
  float4 kpf[4], rkpf[8];
  auto issueKRK = [&](const int j0) {
#pragma unroll
    for (int i2 = 0; i2 < 4; ++i2) {
      const int idx = t + (i2 << 8);
      kpf[i2] = *(const float4*)(k + ((size_t)(bh * SS + j0 + (idx >> 4))) * DD + (idx & 15) * 4);
    }
    const int pLo = j0 - i0 - 63 + 512;
#pragma unroll
    for (int i2 = 0; i2 < 8; ++i2) {
      const int idx = t + (i2 << 8);
      int pp = pLo + (idx >> 4);
      pp = pp < 0 ? 0 : (pp > 512 ? 512 : pp);
      rkpf[i2] = *(const float4*)(RK + (size_t)pp * DD + (idx & 15) * 4);
    }
  };
  auto stageKRKregs = [&]() {
#pragma unroll
    for (int i2 = 0; i2 < 4; ++i2) {
      const int idx = t + (i2 << 8);
      const int row = idx >> 4, c4 = (idx & 15) * 4;
      const float xs[4] = {kpf[i2].x, kpf[i2].y, kpf[i2].z, kpf[i2].w};
      sx4 h, l;
#pragma unroll
      for (int e = 0; e < 4; ++e) {
        const unsigned short hb = f2bf(xs[e]);
        h[e] = (short)hb;
        l[e] = (short)f2bf(xs[e] - bf2f(hb));
      }
      *(sx4*)&sKh[row * 72 + c4] = h;
      *(sx4*)&sKl[row * 72 + c4] = l;
    }
#pragma unroll
    for (int i2 = 0; i2 < 8; ++i2) {
      const int idx = t + (i2 << 8);
      const int u = idx >> 4, c4 = (idx & 15) * 4;
      sx4 h;
      h[0] = (short)f2bf(rkpf[i2].x); h[1] = (short)f2bf(rkpf[i2].y);
      h[2] = (short)f2bf(rkpf[i2].z); h[3] = (short)f2bf(rkpf[i2].w);
      *(sx4*)&sRh[u * 72 + c4] = h;
    }
  };

  // prologue: issue tile-0 K/RK first; their latency soaks under W-zero + Q
  issueKRK(0);

  // zero the fully-masked upper columns of W for this stripe's rows
  {
    const int r = t >> 2, g = t & 3;
    float* Wrow = W + ((size_t)(bh * SS + i0 + r)) * SS;
    float4 z; z.x = z.y = z.z = z.w = 0.f;
    for (int j = (it + 1) * 64 + g * 4; j < SS; j += 16) *(float4*)(Wrow + j) = z;
  }

  // Q fragments (hi/lo split) in registers for this stripe
  sx8 aQh[2], aQl[2];
  {
    const float* qrow = q + ((size_t)(bh * SS + i0 + mt * 16 + lc)) * DD;
#pragma unroll
    for (int ks = 0; ks < 2; ++ks) {
      const int koff = ks * 32 + quad * 8;
      const float4 x0 = *(const float4*)(qrow + koff);
      const float4 x1 = *(const float4*)(qrow + koff + 4);
      const float xs[8] = {x0.x, x0.y, x0.z, x0.w, x1.x, x1.y, x1.z, x1.w};
#pragma unroll
      for (int e = 0; e < 8; ++e) {
        const unsigned short hb = f2bf(xs[e]);
        aQh[ks][e] = (short)hb;
        aQl[ks][e] = (short)f2bf(xs[e] - bf2f(hb));
      }
    }
  }

  const fx4 zz = {0.f, 0.f, 0.f, 0.f};
  float sAcc[4] = {0.f, 0.f, 0.f, 0.f};
  fx4 accO[4] = {zz, zz, zz, zz};

  for (int jt = 0; jt <= it; ++jt) {
    const int j0 = jt * 64;
    const int pLo = j0 - i0 - 63 + 512;
    if (jt) __syncthreads();  // prev tile's LDS reads done
    stageKRKregs();           // convert prefetched regs -> LDS (loads long drained)
    __syncthreads();

    // issue next tile's K/RK now: latency hides under the logits MFMA phase
    if (jt < it) issueKRK(j0 + 64);

    fx4 accS1[4] = {zz, zz, zz, zz};
    fx4 accS2[5] = {zz, zz, zz, zz, zz};
#pragma unroll
    for (int ks = 0; ks < 2; ++ks) {
      const int koff = ks * 32 + quad * 8;
#pragma unroll
      for (int nt = 0; nt < 4; ++nt) {
        const sx8 bKh = *(const sx8*)&sKh[(nt * 16 + lc) * 72 + koff];
        const sx8 bKl = *(const sx8*)&sKl[(nt * 16 + lc) * 72 + koff];
        accS1[nt] = __builtin_amdgcn_mfma_f32_16x16x32_bf16(aQh[ks], bKh, accS1[nt], 0, 0, 0);
        accS1[nt] = __builtin_amdgcn_mfma_f32_16x16x32_bf16(aQl[ks], bKh, accS1[nt], 0, 0, 0);
        accS1[nt] = __builtin_amdgcn_mfma_f32_16x16x32_bf16(aQh[ks], bKl, accS1[nt], 0, 0, 0);
      }
#pragma unroll
      for (int s = 0; s < 5; ++s) {
        const sx8 bR = *(const sx8*)&sRh[((3 - mt + s) * 16 + lc) * 72 + koff];
        accS2[s] = __builtin_amdgcn_mfma_f32_16x16x32_bf16(aQh[ks], bR, accS2[s], 0, 0, 0);
      }
    }
    __syncthreads();  // region0 reads done before overwriting with vT/rvT/wA

    // stage v^T (padded stride 74: conflict-free transpose writes)
    for (int idx = t; idx < 1024; idx += 256) {
      const int jj = idx >> 4, d4 = (idx & 15) * 4;
      const float4 x4 = *(const float4*)(v + ((size_t)(bh * SS + j0 + jj)) * DD + d4);
      vT[(d4 + 0) * 74 + jj] = (short)f2bf(x4.x);
      vT[(d4 + 1) * 74 + jj] = (short)f2bf(x4.y);
      vT[(d4 + 2) * 74 + jj] = (short)f2bf(x4.z);
      vT[(d4 + 3) * 74 + jj] = (short)f2bf(x4.w);
    }
    // stage RVstaged^T (padded stride 138)
    for (int idx = t; idx < 2048; idx += 256) {
      const int u = idx >> 4, d4 = (idx & 15) * 4;
      int pp = pLo + u;
      pp = pp < 0 ? 0 : (pp > 512 ? 512 : pp);
      const float4 x4 = *(const float4*)(RV + (size_t)pp * DD + d4);
      rvT[(d4 + 0) * 138 + u] = (short)f2bf(x4.x);
      rvT[(d4 + 1) * 138 + u] = (short)f2bf(x4.y);
      rvT[(d4 + 2) * 138 + u] = (short)f2bf(x4.z);
      rvT[(d4 + 3) * 138 + u] = (short)f2bf(x4.w);
    }

    // epilogue: w~ = exp(logit), stage wA + wSk, row-sum partials.
#pragma unroll
    for (int nt = 0; nt < 4; ++nt) {
#pragma unroll
      for (int e = 0; e < 4; ++e) {
        const int rr = quad * 4 + e;
        const int du = 63 + lc - rr;
        const int srcLane = (lane & 48) | (du & 15);
        const float g0 = __shfl(accS2[nt][e], srcLane, 64);
        const float g1 = __shfl(accS2[nt + 1][e], srcLane, 64);
        const float val = accS1[nt][e] + (du < 64 ? g0 : g1);
        const int col = j0 + nt * 16 + lc;
        const int rowg = i0 + mt * 16 + rr;
        const float w = (col <= rowg) ? __expf(val) : 0.f;
        sAcc[e] += w;
        const unsigned short h = f2bf(w);
        wA[(mt * 16 + rr) * 72 + nt * 16 + lc] = (short)h;
        wSk[(mt * 16 + rr) * 136 + du + 16 * (nt - mt)] = (short)h;
      }
    }
    __syncthreads();  // staging complete before PV MFMAs / wA readback

    // coalesced W-tile store from wA (256B row segments), before PV so the
    // store retire drains under matrix work
    {
      const int sub = t >> 4;   // 0..15
      const int cq = t & 15;    // 16 lanes -> 64 contiguous floats per row
#pragma unroll
      for (int pass = 0; pass < 4; ++pass) {
        const int row = pass * 16 + sub;
        const sx4 hv = *(const sx4*)&wA[row * 72 + cq * 4];
        float4 o;
        o.x = bf2f((unsigned short)hv[0]);
        o.y = bf2f((unsigned short)hv[1]);
        o.z = bf2f((unsigned short)hv[2]);
        o.w = bf2f((unsigned short)hv[3]);
        *(float4*)(W + ((size_t)(bh * SS + i0 + row)) * SS + j0 + cq * 4) = o;
      }
    }

    // O += w~ @ v   (K = 64 over j)
#pragma unroll
    for (int ks = 0; ks < 2; ++ks) {
      const int koff = ks * 32 + quad * 8;
      const sx8 aW = *(const sx8*)&wA[(mt * 16 + lc) * 72 + koff];
#pragma unroll
      for (int nt = 0; nt < 4; ++nt) {
        const sx8 bV = *(const sx8*)&vT[(nt * 16 + lc) * 74 + koff];
        accO[nt] = __builtin_amdgcn_mfma_f32_16x16x32_bf16(aW, bV, accO[nt], 0, 0, 0);
      }
    }
    // O += w~skew @ RVstaged   (K = 128 over u)
#pragma unroll
    for (int ks = 0; ks < 4; ++ks) {
      const int koff = ks * 32 + quad * 8;
      const sx8 aS = *(const sx8*)&wSk[(mt * 16 + lc) * 136 + koff];
#pragma unroll
      for (int nt = 0; nt < 4; ++nt) {
        const sx8 bR = *(const sx8*)&rvT[(nt * 16 + lc) * 138 + koff];
        accO[nt] = __builtin_amdgcn_mfma_f32_16x16x32_bf16(aS, bR, accO[nt], 0, 0, 0);
      }
    }
  }

  // ---- stripe tail (verified round-6 path) --------------------------------
  __syncthreads();  // full drain: W stores visible, LDS quiesced

  // reduce row-sum partials across the 16 lanes of each quad
#pragma unroll
  for (int off = 1; off <= 8; off <<= 1) {
#pragma unroll
    for (int e = 0; e < 4; ++e) sAcc[e] += __shfl_xor(sAcc[e], off, 64);
  }
  float rI[4];
#pragma unroll
  for (int e = 0; e < 4; ++e) rI[e] = 1.f / sAcc[e];

  // publish row inverses to LDS (reuses wA region; all PV reads drained)
  if (lc == 0) {
#pragma unroll
    for (int e = 0; e < 4; ++e) rowInvLds[mt * 16 + quad * 4 + e] = rI[e];
  }

  // write O scaled by 1/rowSum (registers; no LDS dependency)
#pragma unroll
  for (int nt = 0; nt < 4; ++nt) {
#pragma unroll
    for (int e = 0; e < 4; ++e) {
      O[((size_t)(bh * SS + i0 + mt * 16 + quad * 4 + e)) * DD + nt * 16 + lc] =
          accO[nt][e] * rI[e];
    }
  }

  __syncthreads();  // rowInvLds visible
  __threadfence_block();
  // normalize this block's own 64 W-rows (read*inv, write; coalesced)
  {
    const int r = t >> 2, g = t & 3;
    const float inv = rowInvLds[r];
    float* __restrict__ Wrow = W + ((size_t)(bh * SS + i0 + r)) * SS;
    const int ncol = i0 + 64;
    for (int j = g * 4; j < ncol; j += 16) {
      float4 x = *(const float4*)(Wrow + j);
      x.x *= inv; x.y *= inv; x.z *= inv; x.w *= inv;
      *(float4*)(Wrow + j) = x;
    }
  }
}

extern "C" void kernel_launch(void* const* d_in, const int* in_sizes, int n_in,
                              void* d_out, int out_size, void* d_ws, size_t ws_size,
                              hipStream_t stream) {
  const float* q = (const float*)d_in[0];
  const float* k = (const float*)d_in[1];
  const float* v = (const float*)d_in[2];
  const float* RK = (const float*)d_in[3];  // (1025,64); causal => rows 0..512
  const float* RV = (const float*)d_in[4];

  float* O = (float*)d_out;                         // (B,H,S,D)
  float* W = (float*)d_out + (size_t)BH * SS * DD;  // (B,H,S,S)

  k_fused<<<dim3(16, BH), 256, 0, stream>>>(q, k, v, RK, RV, W, O);
}

// Round 9
// 627.643 us; speedup vs baseline: 1.2944x; 1.2944x over previous
//
#include <hip/hip_runtime.h>
#include <math.h>

#define SS 1024
#define DD 64
#define BH 64

typedef __attribute__((ext_vector_type(4))) float fx4;
typedef __attribute__((ext_vector_type(8))) short sx8;
typedef __attribute__((ext_vector_type(4))) short sx4;

__device__ __forceinline__ unsigned short f2bf(float x) {
  unsigned u = __builtin_bit_cast(unsigned, x);
  u += 0x7fffu + ((u >> 16) & 1u);
  return (unsigned short)(u >> 16);
}
__device__ __forceinline__ float bf2f(unsigned short h) {
  return __builtin_bit_cast(float, ((unsigned)h) << 16);
}

// lgkm-only barrier. The four in-loop phase boundaries order ONLY LDS
// traffic (staging visibility / read-before-overwrite / wA visibility), so
// the vmcnt(0) drain that __syncthreads forces — waiting out W-store acks
// and staging-load retires every tile — is pure waste there. sched_barrier
// on both sides per rule #18 (hipcc can hoist register-only MFMA past an
// inline-asm wait). Tail barriers stay full __syncthreads (W readback
// genuinely needs the vmcnt drain).
#define BAR_LGKM()                                          \
  do {                                                      \
    asm volatile("s_waitcnt lgkmcnt(0)" ::: "memory");      \
    __builtin_amdgcn_sched_barrier(0);                      \
    __builtin_amdgcn_s_barrier();                           \
    __builtin_amdgcn_sched_barrier(0);                      \
  } while (0)

// ---------------------------------------------------------------------------
// Round-9 = VERIFIED round-6 kernel (377 us, passed) with exactly one change
// class: the 4 in-loop __syncthreads -> lgkm-only barriers. Everything else
// (LDS layout/aliasing, staging, epilogue, coalesced W-store, tail, paired
// stripes, 512 blocks, launch_bounds(256,3)) is byte-identical to round 6.
// ---------------------------------------------------------------------------
__global__ __launch_bounds__(256, 3) void k_fused(
    const float* __restrict__ q, const float* __restrict__ k,
    const float* __restrict__ v, const float* __restrict__ RK,
    const float* __restrict__ RV, float* __restrict__ W, float* __restrict__ O) {
  // XCD-contiguous remap: 512 blocks, XCD x -> bh in [8x,8x+8), all 8 pairs
  const int bid = (blockIdx.y << 3) | blockIdx.x;
  const int nb = ((bid & 7) << 6) | (bid >> 3);
  const int p = nb & 7, bh = nb >> 3;

  __shared__ __align__(16) char smem[54272];
  short* const sKh = (short*)smem;            // [64*72]
  short* const sKl = (short*)(smem + 9216);   // [64*72]
  short* const sRh = (short*)(smem + 18432);  // [128*72]          ends 36864
  short* const vT  = (short*)smem;            // [64*74]  (aliases sKh..)
  short* const rvT = (short*)(smem + 9472);   // [64*138] (aliases sKl/sRh)
  short* const wA  = (short*)(smem + 27136);  // [64*72]  ends 36352
  short* const wSk = (short*)(smem + 36864);  // [64*136] exclusive, ends 54272
  float* const rowInvLds = (float*)(smem + 27136);  // [64] tail-only (reuses wA)

  const int t = threadIdx.x;
  const int lane = t & 63, mt = t >> 6, quad = lane >> 4, lc = lane & 15;

  // one-time: zero the never-valid wSk slots (wave-private rows; no barrier)
#pragma unroll
  for (int e = 0; e < 4; ++e) {
    const int rr = quad * 4 + e;
    const int rloc = mt * 16 + rr;
    const int du = 63 + lc - rr;         // [48,78]
    const int us0 = du & 15;
    const int A = (du >> 4) - mt;        // valid kk = nt + A, nt=0..3
#pragma unroll
    for (int kk = 0; kk < 8; ++kk) {
      if (kk < A || kk > A + 3) wSk[rloc * 136 + us0 + 16 * kk] = 0;
    }
  }

  auto stageKRK = [&](const int j0, const int i0) {
    for (int idx = t; idx < 1024; idx += 256) {
      const int row = idx >> 4, c4 = (idx & 15) * 4;
      const float4 x = *(const float4*)(k + ((size_t)(bh * SS + j0 + row)) * DD + c4);
      const float xs[4] = {x.x, x.y, x.z, x.w};
      sx4 h, l;
#pragma unroll
      for (int e = 0; e < 4; ++e) {
        const unsigned short hb = f2bf(xs[e]);
        h[e] = (short)hb;
        l[e] = (short)f2bf(xs[e] - bf2f(hb));
      }
      *(sx4*)&sKh[row * 72 + c4] = h;
      *(sx4*)&sKl[row * 72 + c4] = l;
    }
    const int pLo = j0 - i0 - 63 + 512;
    for (int idx = t; idx < 2048; idx += 256) {
      const int u = idx >> 4, c4 = (idx & 15) * 4;
      int pp = pLo + u;
      pp = pp < 0 ? 0 : (pp > 512 ? 512 : pp);
      const float4 x = *(const float4*)(RK + (size_t)pp * DD + c4);
      sx4 h;
      h[0] = (short)f2bf(x.x); h[1] = (short)f2bf(x.y);
      h[2] = (short)f2bf(x.z); h[3] = (short)f2bf(x.w);
      *(sx4*)&sRh[u * 72 + c4] = h;
    }
  };

  for (int half = 0; half < 2; ++half) {
    const int it = half ? 15 - p : p;
    const int i0 = it << 6;

    // zero the fully-masked upper columns of W for this stripe's rows
    {
      const int r = t >> 2, g = t & 3;
      float* Wrow = W + ((size_t)(bh * SS + i0 + r)) * SS;
      float4 z; z.x = z.y = z.z = z.w = 0.f;
      for (int j = (it + 1) * 64 + g * 4; j < SS; j += 16) *(float4*)(Wrow + j) = z;
    }

    // Q fragments (hi/lo split) in registers for this stripe
    sx8 aQh[2], aQl[2];
    {
      const float* qrow = q + ((size_t)(bh * SS + i0 + mt * 16 + lc)) * DD;
#pragma unroll
      for (int ks = 0; ks < 2; ++ks) {
        const int koff = ks * 32 + quad * 8;
        const float4 x0 = *(const float4*)(qrow + koff);
        const float4 x1 = *(const float4*)(qrow + koff + 4);
        const float xs[8] = {x0.x, x0.y, x0.z, x0.w, x1.x, x1.y, x1.z, x1.w};
#pragma unroll
        for (int e = 0; e < 8; ++e) {
          const unsigned short hb = f2bf(xs[e]);
          aQh[ks][e] = (short)hb;
          aQl[ks][e] = (short)f2bf(xs[e] - bf2f(hb));
        }
      }
    }

    const fx4 zz = {0.f, 0.f, 0.f, 0.f};
    float sAcc[4] = {0.f, 0.f, 0.f, 0.f};
    fx4 accO[4] = {zz, zz, zz, zz};

    for (int jt = 0; jt <= it; ++jt) {
      const int j0 = jt * 64;
      const int pLo = j0 - i0 - 63 + 512;
      if (jt | half) BAR_LGKM();  // prev tile's (or prev tail's) LDS reads done
      stageKRK(j0, i0);
      BAR_LGKM();  // staged K/RK visible block-wide

      fx4 accS1[4] = {zz, zz, zz, zz};
      fx4 accS2[5] = {zz, zz, zz, zz, zz};
#pragma unroll
      for (int ks = 0; ks < 2; ++ks) {
        const int koff = ks * 32 + quad * 8;
#pragma unroll
        for (int nt = 0; nt < 4; ++nt) {
          const sx8 bKh = *(const sx8*)&sKh[(nt * 16 + lc) * 72 + koff];
          const sx8 bKl = *(const sx8*)&sKl[(nt * 16 + lc) * 72 + koff];
          accS1[nt] = __builtin_amdgcn_mfma_f32_16x16x32_bf16(aQh[ks], bKh, accS1[nt], 0, 0, 0);
          accS1[nt] = __builtin_amdgcn_mfma_f32_16x16x32_bf16(aQl[ks], bKh, accS1[nt], 0, 0, 0);
          accS1[nt] = __builtin_amdgcn_mfma_f32_16x16x32_bf16(aQh[ks], bKl, accS1[nt], 0, 0, 0);
        }
#pragma unroll
        for (int s = 0; s < 5; ++s) {
          const sx8 bR = *(const sx8*)&sRh[((3 - mt + s) * 16 + lc) * 72 + koff];
          accS2[s] = __builtin_amdgcn_mfma_f32_16x16x32_bf16(aQh[ks], bR, accS2[s], 0, 0, 0);
        }
      }
      BAR_LGKM();  // logits LDS reads done before overwriting with vT/rvT/wA

      // stage v^T (padded stride 74: conflict-free transpose writes)
      for (int idx = t; idx < 1024; idx += 256) {
        const int jj = idx >> 4, d4 = (idx & 15) * 4;
        const float4 x4 = *(const float4*)(v + ((size_t)(bh * SS + j0 + jj)) * DD + d4);
        vT[(d4 + 0) * 74 + jj] = (short)f2bf(x4.x);
        vT[(d4 + 1) * 74 + jj] = (short)f2bf(x4.y);
        vT[(d4 + 2) * 74 + jj] = (short)f2bf(x4.z);
        vT[(d4 + 3) * 74 + jj] = (short)f2bf(x4.w);
      }
      // stage RVstaged^T (padded stride 138)
      for (int idx = t; idx < 2048; idx += 256) {
        const int u = idx >> 4, d4 = (idx & 15) * 4;
        int pp = pLo + u;
        pp = pp < 0 ? 0 : (pp > 512 ? 512 : pp);
        const float4 x4 = *(const float4*)(RV + (size_t)pp * DD + d4);
        rvT[(d4 + 0) * 138 + u] = (short)f2bf(x4.x);
        rvT[(d4 + 1) * 138 + u] = (short)f2bf(x4.y);
        rvT[(d4 + 2) * 138 + u] = (short)f2bf(x4.z);
        rvT[(d4 + 3) * 138 + u] = (short)f2bf(x4.w);
      }

      // epilogue: w~ = exp(logit), stage wA + wSk, row-sum partials.
#pragma unroll
      for (int nt = 0; nt < 4; ++nt) {
#pragma unroll
        for (int e = 0; e < 4; ++e) {
          const int rr = quad * 4 + e;
          const int du = 63 + lc - rr;
          const int srcLane = (lane & 48) | (du & 15);
          const float g0 = __shfl(accS2[nt][e], srcLane, 64);
          const float g1 = __shfl(accS2[nt + 1][e], srcLane, 64);
          const float val = accS1[nt][e] + (du < 64 ? g0 : g1);
          const int col = j0 + nt * 16 + lc;
          const int rowg = i0 + mt * 16 + rr;
          const float w = (col <= rowg) ? __expf(val) : 0.f;
          sAcc[e] += w;
          const unsigned short h = f2bf(w);
          wA[(mt * 16 + rr) * 72 + nt * 16 + lc] = (short)h;
          wSk[(mt * 16 + rr) * 136 + du + 16 * (nt - mt)] = (short)h;
        }
      }
      BAR_LGKM();  // vT/rvT/wA/wSk staged before PV MFMAs / wA readback

      // coalesced W-tile store from wA (256B row segments), before PV so the
      // store retire drains under matrix work
      {
        const int sub = t >> 4;   // 0..15
        const int cq = t & 15;    // 16 lanes -> 64 contiguous floats per row
#pragma unroll
        for (int pass = 0; pass < 4; ++pass) {
          const int row = pass * 16 + sub;
          const sx4 hv = *(const sx4*)&wA[row * 72 + cq * 4];
          float4 o;
          o.x = bf2f((unsigned short)hv[0]);
          o.y = bf2f((unsigned short)hv[1]);
          o.z = bf2f((unsigned short)hv[2]);
          o.w = bf2f((unsigned short)hv[3]);
          *(float4*)(W + ((size_t)(bh * SS + i0 + row)) * SS + j0 + cq * 4) = o;
        }
      }

      // O += w~ @ v   (K = 64 over j)
#pragma unroll
      for (int ks = 0; ks < 2; ++ks) {
        const int koff = ks * 32 + quad * 8;
        const sx8 aW = *(const sx8*)&wA[(mt * 16 + lc) * 72 + koff];
#pragma unroll
        for (int nt = 0; nt < 4; ++nt) {
          const sx8 bV = *(const sx8*)&vT[(nt * 16 + lc) * 74 + koff];
          accO[nt] = __builtin_amdgcn_mfma_f32_16x16x32_bf16(aW, bV, accO[nt], 0, 0, 0);
        }
      }
      // O += w~skew @ RVstaged   (K = 128 over u)
#pragma unroll
      for (int ks = 0; ks < 4; ++ks) {
        const int koff = ks * 32 + quad * 8;
        const sx8 aS = *(const sx8*)&wSk[(mt * 16 + lc) * 136 + koff];
#pragma unroll
        for (int nt = 0; nt < 4; ++nt) {
          const sx8 bR = *(const sx8*)&rvT[(nt * 16 + lc) * 138 + koff];
          accO[nt] = __builtin_amdgcn_mfma_f32_16x16x32_bf16(aS, bR, accO[nt], 0, 0, 0);
        }
      }
    }

    // ---- stripe tail (cold path: FULL barriers — vmcnt drain needed) -----
    __syncthreads();  // all W-stores retired & visible; LDS quiesced

    // reduce row-sum partials across the 16 lanes of each quad
#pragma unroll
    for (int off = 1; off <= 8; off <<= 1) {
#pragma unroll
      for (int e = 0; e < 4; ++e) sAcc[e] += __shfl_xor(sAcc[e], off, 64);
    }
    float rI[4];
#pragma unroll
    for (int e = 0; e < 4; ++e) rI[e] = 1.f / sAcc[e];

    // publish row inverses to LDS (reuses wA region; all PV reads drained)
    if (lc == 0) {
#pragma unroll
      for (int e = 0; e < 4; ++e) rowInvLds[mt * 16 + quad * 4 + e] = rI[e];
    }

    // write O scaled by 1/rowSum (registers; no LDS dependency)
#pragma unroll
    for (int nt = 0; nt < 4; ++nt) {
#pragma unroll
      for (int e = 0; e < 4; ++e) {
        O[((size_t)(bh * SS + i0 + mt * 16 + quad * 4 + e)) * DD + nt * 16 + lc] =
            accO[nt][e] * rI[e];
      }
    }

    __syncthreads();  // rowInvLds visible
    __threadfence_block();
    // normalize this block's own 64 W-rows (read*inv, write; coalesced)
    {
      const int r = t >> 2, g = t & 3;
      const float inv = rowInvLds[r];
      float* __restrict__ Wrow = W + ((size_t)(bh * SS + i0 + r)) * SS;
      const int ncol = i0 + 64;
      for (int j = g * 4; j < ncol; j += 16) {
        float4 x = *(const float4*)(Wrow + j);
        x.x *= inv; x.y *= inv; x.z *= inv; x.w *= inv;
        *(float4*)(Wrow + j) = x;
      }
    }
    __syncthreads();  // tail LDS reads done before next half overwrites
  }
}

extern "C" void kernel_launch(void* const* d_in, const int* in_sizes, int n_in,
                              void* d_out, int out_size, void* d_ws, size_t ws_size,
                              hipStream_t stream) {
  const float* q = (const float*)d_in[0];
  const float* k = (const float*)d_in[1];
  const float* v = (const float*)d_in[2];
  const float* RK = (const float*)d_in[3];  // (1025,64); causal => rows 0..512
  const float* RV = (const float*)d_in[4];

  float* O = (float*)d_out;                         // (B,H,S,D)
  float* W = (float*)d_out + (size_t)BH * SS * DD;  // (B,H,S,S)

  k_fused<<<dim3(8, BH), 256, 0, stream>>>(q, k, v, RK, RV, W, O);
}

// Round 10
// 621.273 us; speedup vs baseline: 1.3076x; 1.0103x over previous
//
#include <hip/hip_runtime.h>
#include <math.h>

#define SS 1024
#define DD 64
#define BH 64

typedef __attribute__((ext_vector_type(4))) float fx4;
typedef __attribute__((ext_vector_type(8))) short sx8;
typedef __attribute__((ext_vector_type(4))) short sx4;

__device__ __forceinline__ unsigned short f2bf(float x) {
  unsigned u = __builtin_bit_cast(unsigned, x);
  u += 0x7fffu + ((u >> 16) & 1u);
  return (unsigned short)(u >> 16);
}
__device__ __forceinline__ float bf2f(unsigned short h) {
  return __builtin_bit_cast(float, ((unsigned)h) << 16);
}

// lgkm-only barrier (r9, verified): in-loop phase boundaries order only LDS.
// vmcnt is NOT drained -> prefetched global loads stay in flight across
// barriers. sched_barrier(0) per rule #18.
#define BAR_LGKM()                                          \
  do {                                                      \
    asm volatile("s_waitcnt lgkmcnt(0)" ::: "memory");      \
    __builtin_amdgcn_sched_barrier(0);                      \
    __builtin_amdgcn_s_barrier();                           \
    __builtin_amdgcn_sched_barrier(0);                      \
  } while (0)

// ---------------------------------------------------------------------------
// Round-10 = VERIFIED round-9 frame (380 us, passed: lgkm in-loop barriers,
// full __syncthreads tail, paired 512 blocks, LDS 54272 aliased layout,
// identical arithmetic) + two latency levers:
//  1) REAL one-tile-ahead register prefetch of K/RK/V/RV (24 float4, wave-
//     private). Issue sites pinned with sched_barrier so the compiler cannot
//     sink the loads to their use (r7's failure: VGPR stayed 84 = sunk).
//     With lgkm-only in-loop barriers the loads fly for a full tile.
//     VGPR tell: expect ~180.
//  2) Contiguous streaming for zero-fill and tail-normalize: wave-per-row
//     (64 lanes x 16B = 1KB/instruction) instead of 16 rows x 16B scattered
//     segments at 4KB stride. Same bytes, same arithmetic; pure DRAM/L2
//     access-pattern fix for ~394MB of the 580MB total traffic.
// ---------------------------------------------------------------------------
__global__ __launch_bounds__(256, 2) void k_fused(
    const float* __restrict__ q, const float* __restrict__ k,
    const float* __restrict__ v, const float* __restrict__ RK,
    const float* __restrict__ RV, float* __restrict__ W, float* __restrict__ O) {
  // XCD-contiguous remap: 512 blocks, XCD x -> bh in [8x,8x+8), all 8 pairs
  const int bid = (blockIdx.y << 3) | blockIdx.x;
  const int nb = ((bid & 7) << 6) | (bid >> 3);
  const int p = nb & 7, bh = nb >> 3;

  __shared__ __align__(16) char smem[54272];
  short* const sKh = (short*)smem;            // [64*72]
  short* const sKl = (short*)(smem + 9216);   // [64*72]
  short* const sRh = (short*)(smem + 18432);  // [128*72]          ends 36864
  short* const vT  = (short*)smem;            // [64*74]  (aliases sKh..)
  short* const rvT = (short*)(smem + 9472);   // [64*138] (aliases sKl/sRh)
  short* const wA  = (short*)(smem + 27136);  // [64*72]  ends 36352
  short* const wSk = (short*)(smem + 36864);  // [64*136] exclusive, ends 54272
  float* const rowInvLds = (float*)(smem + 27136);  // [64] tail-only (reuses wA)

  const int t = threadIdx.x;
  const int lane = t & 63, mt = t >> 6, quad = lane >> 4, lc = lane & 15;

  // one-time: zero the never-valid wSk slots (wave-private rows; no barrier)
#pragma unroll
  for (int e = 0; e < 4; ++e) {
    const int rr = quad * 4 + e;
    const int rloc = mt * 16 + rr;
    const int du = 63 + lc - rr;         // [48,78]
    const int us0 = du & 15;
    const int A = (du >> 4) - mt;        // valid kk = nt + A, nt=0..3
#pragma unroll
    for (int kk = 0; kk < 8; ++kk) {
      if (kk < A || kk > A + 3) wSk[rloc * 136 + us0 + 16 * kk] = 0;
    }
  }

  // ---- one-tile-ahead prefetch registers (wave-private) -------------------
  float4 kpf[4], rkpf[8], vpf[4], rvpf[8];

  auto issueKRK = [&](const int j0, const int i0) {
#pragma unroll
    for (int i2 = 0; i2 < 4; ++i2) {
      const int idx = t + (i2 << 8);
      kpf[i2] = *(const float4*)(k + ((size_t)(bh * SS + j0 + (idx >> 4))) * DD + (idx & 15) * 4);
    }
    const int pLo = j0 - i0 - 63 + 512;
#pragma unroll
    for (int i2 = 0; i2 < 8; ++i2) {
      const int idx = t + (i2 << 8);
      int pp = pLo + (idx >> 4);
      pp = pp < 0 ? 0 : (pp > 512 ? 512 : pp);
      rkpf[i2] = *(const float4*)(RK + (size_t)pp * DD + (idx & 15) * 4);
    }
    __builtin_amdgcn_sched_barrier(0);  // pin issue here (r7: sunk without)
  };
  auto issueVRV = [&](const int j0, const int i0) {
#pragma unroll
    for (int i2 = 0; i2 < 4; ++i2) {
      const int idx = t + (i2 << 8);
      vpf[i2] = *(const float4*)(v + ((size_t)(bh * SS + j0 + (idx >> 4))) * DD + (idx & 15) * 4);
    }
    const int pLo = j0 - i0 - 63 + 512;
#pragma unroll
    for (int i2 = 0; i2 < 8; ++i2) {
      const int idx = t + (i2 << 8);
      int pp = pLo + (idx >> 4);
      pp = pp < 0 ? 0 : (pp > 512 ? 512 : pp);
      rvpf[i2] = *(const float4*)(RV + (size_t)pp * DD + (idx & 15) * 4);
    }
    __builtin_amdgcn_sched_barrier(0);
  };

  // convert prefetched K/RK regs -> LDS (loads issued a full tile ago)
  auto stageKRKregs = [&]() {
#pragma unroll
    for (int i2 = 0; i2 < 4; ++i2) {
      const int idx = t + (i2 << 8);
      const int row = idx >> 4, c4 = (idx & 15) * 4;
      const float xs[4] = {kpf[i2].x, kpf[i2].y, kpf[i2].z, kpf[i2].w};
      sx4 h, l;
#pragma unroll
      for (int e = 0; e < 4; ++e) {
        const unsigned short hb = f2bf(xs[e]);
        h[e] = (short)hb;
        l[e] = (short)f2bf(xs[e] - bf2f(hb));
      }
      *(sx4*)&sKh[row * 72 + c4] = h;
      *(sx4*)&sKl[row * 72 + c4] = l;
    }
#pragma unroll
    for (int i2 = 0; i2 < 8; ++i2) {
      const int idx = t + (i2 << 8);
      const int u = idx >> 4, c4 = (idx & 15) * 4;
      sx4 h;
      h[0] = (short)f2bf(rkpf[i2].x); h[1] = (short)f2bf(rkpf[i2].y);
      h[2] = (short)f2bf(rkpf[i2].z); h[3] = (short)f2bf(rkpf[i2].w);
      *(sx4*)&sRh[u * 72 + c4] = h;
    }
  };

  // prologue: issue half-0 tile-0 loads; latency soaks under zero + Q phases
  issueKRK(0, p << 6);
  issueVRV(0, p << 6);

  for (int half = 0; half < 2; ++half) {
    const int it = half ? 15 - p : p;
    const int i0 = it << 6;

    // zero the fully-masked upper W columns: wave-per-row, 1KB contiguous
    // per instruction (was 16 rows x 16B scattered at 4KB stride)
    {
      float4 z; z.x = z.y = z.z = z.w = 0.f;
      for (int r = mt; r < 64; r += 4) {
        float* Wrow = W + ((size_t)(bh * SS + i0 + r)) * SS;
        for (int j = (it + 1) * 64 + lane * 4; j < SS; j += 256)
          *(float4*)(Wrow + j) = z;
      }
    }

    // Q fragments (hi/lo split) in registers for this stripe
    sx8 aQh[2], aQl[2];
    {
      const float* qrow = q + ((size_t)(bh * SS + i0 + mt * 16 + lc)) * DD;
#pragma unroll
      for (int ks = 0; ks < 2; ++ks) {
        const int koff = ks * 32 + quad * 8;
        const float4 x0 = *(const float4*)(qrow + koff);
        const float4 x1 = *(const float4*)(qrow + koff + 4);
        const float xs[8] = {x0.x, x0.y, x0.z, x0.w, x1.x, x1.y, x1.z, x1.w};
#pragma unroll
        for (int e = 0; e < 8; ++e) {
          const unsigned short hb = f2bf(xs[e]);
          aQh[ks][e] = (short)hb;
          aQl[ks][e] = (short)f2bf(xs[e] - bf2f(hb));
        }
      }
    }

    const fx4 zz = {0.f, 0.f, 0.f, 0.f};
    float sAcc[4] = {0.f, 0.f, 0.f, 0.f};
    fx4 accO[4] = {zz, zz, zz, zz};

    for (int jt = 0; jt <= it; ++jt) {
      const int j0 = jt * 64;
      if (jt | half) BAR_LGKM();  // prev tile's (or prev tail's) LDS reads done
      stageKRKregs();
      // issue NEXT K/RK now: flies across the lgkm barriers, lands during
      // logits/epilogue, consumed at next tile's stageKRKregs
      if (jt < it) issueKRK(j0 + 64, i0);
      else if (half == 0) issueKRK(0, (15 - p) << 6);
      BAR_LGKM();  // staged K/RK visible block-wide

      fx4 accS1[4] = {zz, zz, zz, zz};
      fx4 accS2[5] = {zz, zz, zz, zz, zz};
#pragma unroll
      for (int ks = 0; ks < 2; ++ks) {
        const int koff = ks * 32 + quad * 8;
#pragma unroll
        for (int nt = 0; nt < 4; ++nt) {
          const sx8 bKh = *(const sx8*)&sKh[(nt * 16 + lc) * 72 + koff];
          const sx8 bKl = *(const sx8*)&sKl[(nt * 16 + lc) * 72 + koff];
          accS1[nt] = __builtin_amdgcn_mfma_f32_16x16x32_bf16(aQh[ks], bKh, accS1[nt], 0, 0, 0);
          accS1[nt] = __builtin_amdgcn_mfma_f32_16x16x32_bf16(aQl[ks], bKh, accS1[nt], 0, 0, 0);
          accS1[nt] = __builtin_amdgcn_mfma_f32_16x16x32_bf16(aQh[ks], bKl, accS1[nt], 0, 0, 0);
        }
#pragma unroll
        for (int s = 0; s < 5; ++s) {
          const sx8 bR = *(const sx8*)&sRh[((3 - mt + s) * 16 + lc) * 72 + koff];
          accS2[s] = __builtin_amdgcn_mfma_f32_16x16x32_bf16(aQh[ks], bR, accS2[s], 0, 0, 0);
        }
      }
      BAR_LGKM();  // logits LDS reads done before overwriting with vT/rvT/wA

      // stage v^T / rvT^T from prefetched regs (padded strides 74/138)
#pragma unroll
      for (int i2 = 0; i2 < 4; ++i2) {
        const int idx = t + (i2 << 8);
        const int jj = idx >> 4, d4 = (idx & 15) * 4;
        vT[(d4 + 0) * 74 + jj] = (short)f2bf(vpf[i2].x);
        vT[(d4 + 1) * 74 + jj] = (short)f2bf(vpf[i2].y);
        vT[(d4 + 2) * 74 + jj] = (short)f2bf(vpf[i2].z);
        vT[(d4 + 3) * 74 + jj] = (short)f2bf(vpf[i2].w);
      }
#pragma unroll
      for (int i2 = 0; i2 < 8; ++i2) {
        const int idx = t + (i2 << 8);
        const int u = idx >> 4, d4 = (idx & 15) * 4;
        rvT[(d4 + 0) * 138 + u] = (short)f2bf(rvpf[i2].x);
        rvT[(d4 + 1) * 138 + u] = (short)f2bf(rvpf[i2].y);
        rvT[(d4 + 2) * 138 + u] = (short)f2bf(rvpf[i2].z);
        rvT[(d4 + 3) * 138 + u] = (short)f2bf(rvpf[i2].w);
      }
      // issue NEXT V/RV: consumed next tile after two barriers
      if (jt < it) issueVRV(j0 + 64, i0);
      else if (half == 0) issueVRV(0, (15 - p) << 6);

      // epilogue: w~ = exp(logit), stage wA + wSk, row-sum partials
#pragma unroll
      for (int nt = 0; nt < 4; ++nt) {
#pragma unroll
        for (int e = 0; e < 4; ++e) {
          const int rr = quad * 4 + e;
          const int du = 63 + lc - rr;
          const int srcLane = (lane & 48) | (du & 15);
          const float g0 = __shfl(accS2[nt][e], srcLane, 64);
          const float g1 = __shfl(accS2[nt + 1][e], srcLane, 64);
          const float val = accS1[nt][e] + (du < 64 ? g0 : g1);
          const int col = j0 + nt * 16 + lc;
          const int rowg = i0 + mt * 16 + rr;
          const float w = (col <= rowg) ? __expf(val) : 0.f;
          sAcc[e] += w;
          const unsigned short h = f2bf(w);
          wA[(mt * 16 + rr) * 72 + nt * 16 + lc] = (short)h;
          wSk[(mt * 16 + rr) * 136 + du + 16 * (nt - mt)] = (short)h;
        }
      }
      BAR_LGKM();  // vT/rvT/wA/wSk staged before PV MFMAs / wA readback

      // coalesced W-tile store from wA (256B row segments), before PV so the
      // store retire drains under matrix work
      {
        const int sub = t >> 4;   // 0..15
        const int cq = t & 15;    // 16 lanes -> 64 contiguous floats per row
#pragma unroll
        for (int pass = 0; pass < 4; ++pass) {
          const int row = pass * 16 + sub;
          const sx4 hv = *(const sx4*)&wA[row * 72 + cq * 4];
          float4 o;
          o.x = bf2f((unsigned short)hv[0]);
          o.y = bf2f((unsigned short)hv[1]);
          o.z = bf2f((unsigned short)hv[2]);
          o.w = bf2f((unsigned short)hv[3]);
          *(float4*)(W + ((size_t)(bh * SS + i0 + row)) * SS + j0 + cq * 4) = o;
        }
      }

      // O += w~ @ v   (K = 64 over j)
#pragma unroll
      for (int ks = 0; ks < 2; ++ks) {
        const int koff = ks * 32 + quad * 8;
        const sx8 aW = *(const sx8*)&wA[(mt * 16 + lc) * 72 + koff];
#pragma unroll
        for (int nt = 0; nt < 4; ++nt) {
          const sx8 bV = *(const sx8*)&vT[(nt * 16 + lc) * 74 + koff];
          accO[nt] = __builtin_amdgcn_mfma_f32_16x16x32_bf16(aW, bV, accO[nt], 0, 0, 0);
        }
      }
      // O += w~skew @ RVstaged   (K = 128 over u)
#pragma unroll
      for (int ks = 0; ks < 4; ++ks) {
        const int koff = ks * 32 + quad * 8;
        const sx8 aS = *(const sx8*)&wSk[(mt * 16 + lc) * 136 + koff];
#pragma unroll
        for (int nt = 0; nt < 4; ++nt) {
          const sx8 bR = *(const sx8*)&rvT[(nt * 16 + lc) * 138 + koff];
          accO[nt] = __builtin_amdgcn_mfma_f32_16x16x32_bf16(aS, bR, accO[nt], 0, 0, 0);
        }
      }
    }

    // ---- stripe tail (cold path: FULL barriers — vmcnt drain needed) -----
    __syncthreads();  // all W-stores retired & visible; LDS quiesced

    // reduce row-sum partials across the 16 lanes of each quad
#pragma unroll
    for (int off = 1; off <= 8; off <<= 1) {
#pragma unroll
      for (int e = 0; e < 4; ++e) sAcc[e] += __shfl_xor(sAcc[e], off, 64);
    }
    float rI[4];
#pragma unroll
    for (int e = 0; e < 4; ++e) rI[e] = 1.f / sAcc[e];

    // publish row inverses to LDS (reuses wA region; all PV reads drained)
    if (lc == 0) {
#pragma unroll
      for (int e = 0; e < 4; ++e) rowInvLds[mt * 16 + quad * 4 + e] = rI[e];
    }

    // write O scaled by 1/rowSum (registers; no LDS dependency)
#pragma unroll
    for (int nt = 0; nt < 4; ++nt) {
#pragma unroll
      for (int e = 0; e < 4; ++e) {
        O[((size_t)(bh * SS + i0 + mt * 16 + quad * 4 + e)) * DD + nt * 16 + lc] =
            accO[nt][e] * rI[e];
      }
    }

    __syncthreads();  // rowInvLds visible
    __threadfence_block();
    // normalize this block's 64 W-rows: wave-per-row, 1KB contiguous per
    // instruction (was 16 rows x 16B scattered at 4KB stride)
    {
      const int ncol = i0 + 64;
      for (int r = mt; r < 64; r += 4) {
        const float inv = rowInvLds[r];
        float* __restrict__ Wrow = W + ((size_t)(bh * SS + i0 + r)) * SS;
        for (int j = lane * 4; j < ncol; j += 256) {
          float4 x = *(const float4*)(Wrow + j);
          x.x *= inv; x.y *= inv; x.z *= inv; x.w *= inv;
          *(float4*)(Wrow + j) = x;
        }
      }
    }
    __syncthreads();  // tail LDS reads done before next half overwrites
  }
}

extern "C" void kernel_launch(void* const* d_in, const int* in_sizes, int n_in,
                              void* d_out, int out_size, void* d_ws, size_t ws_size,
                              hipStream_t stream) {
  const float* q = (const float*)d_in[0];
  const float* k = (const float*)d_in[1];
  const float* v = (const float*)d_in[2];
  const float* RK = (const float*)d_in[3];  // (1025,64); causal => rows 0..512
  const float* RV = (const float*)d_in[4];

  float* O = (float*)d_out;                         // (B,H,S,D)
  float* W = (float*)d_out + (size_t)BH * SS * DD;  // (B,H,S,S)

  k_fused<<<dim3(8, BH), 256, 0, stream>>>(q, k, v, RK, RV, W, O);
}

// Round 11
// 547.384 us; speedup vs baseline: 1.4842x; 1.1350x over previous
//
#include <hip/hip_runtime.h>
#include <math.h>

#define SS 1024
#define DD 64
#define BH 64

typedef __attribute__((ext_vector_type(4))) float fx4;
typedef __attribute__((ext_vector_type(8))) short sx8;
typedef __attribute__((ext_vector_type(4))) short sx4;

__device__ __forceinline__ unsigned short f2bf(float x) {
  unsigned u = __builtin_bit_cast(unsigned, x);
  u += 0x7fffu + ((u >> 16) & 1u);
  return (unsigned short)(u >> 16);
}
__device__ __forceinline__ float bf2f(unsigned short h) {
  return __builtin_bit_cast(float, ((unsigned)h) << 16);
}

// lgkm-only barrier (r9/r10, verified): in-loop boundaries order only LDS;
// vmcnt not drained (prefetch + W-stores stay in flight). rule #18 fences.
#define BAR_LGKM()                                          \
  do {                                                      \
    asm volatile("s_waitcnt lgkmcnt(0)" ::: "memory");      \
    __builtin_amdgcn_sched_barrier(0);                      \
    __builtin_amdgcn_s_barrier();                           \
    __builtin_amdgcn_sched_barrier(0);                      \
  } while (0)

// ---------------------------------------------------------------------------
// Round-11 = r10 frame (365 us, passed) with the sync surface REDUCED:
//  * vT/rvT un-aliased from the K region (LDS 54272 -> 81408; 2 blocks/CU,
//    footprint launch-verified in r5) and staged in phase A with K/RK.
//  * W written directly from epilogue registers (scattered; r6 proved equal
//    to coalesced) -> wA/wSk have no cross-wave readers.
//  => per tile: [BAR] stage [BAR] logits [BAR] epilogue+Wstore+PV (sync-free)
//  3 lgkm barriers instead of 4, and the heaviest phase has no cross-wave
//  sync at all -> waves drift, VALU/LDS/MFMA pipes overlap across waves.
// Everything else (prefetch, arithmetic, tail, paired stripes) = r10.
// ---------------------------------------------------------------------------
__global__ __launch_bounds__(256, 2) void k_fused(
    const float* __restrict__ q, const float* __restrict__ k,
    const float* __restrict__ v, const float* __restrict__ RK,
    const float* __restrict__ RV, float* __restrict__ W, float* __restrict__ O) {
  // XCD-contiguous remap: 512 blocks, XCD x -> bh in [8x,8x+8), all 8 pairs
  const int bid = (blockIdx.y << 3) | blockIdx.x;
  const int nb = ((bid & 7) << 6) | (bid >> 3);
  const int p = nb & 7, bh = nb >> 3;

  __shared__ __align__(16) char smem[81408];
  short* const sKh = (short*)smem;            // [64*72]   0..9216
  short* const sKl = (short*)(smem + 9216);   // [64*72]   ..18432
  short* const sRh = (short*)(smem + 18432);  // [128*72]  ..36864
  short* const vT  = (short*)(smem + 36864);  // [64*74]   ..46336
  short* const rvT = (short*)(smem + 46336);  // [64*138]  ..64000
  short* const wSk = (short*)(smem + 64000);  // [64*136]  ..81408
  short* const wA  = (short*)smem;            // [64*72] aliases sKh (dead after b2)
  float* const rowInvLds = (float*)(smem + 36864);  // [64] tail-only (aliases vT)

  const int t = threadIdx.x;
  const int lane = t & 63, mt = t >> 6, quad = lane >> 4, lc = lane & 15;

  // one-time: zero the never-valid wSk slots (wave-private rows; no barrier)
#pragma unroll
  for (int e = 0; e < 4; ++e) {
    const int rr = quad * 4 + e;
    const int rloc = mt * 16 + rr;
    const int du = 63 + lc - rr;         // [48,78]
    const int us0 = du & 15;
    const int A = (du >> 4) - mt;        // valid kk = nt + A, nt=0..3
#pragma unroll
    for (int kk = 0; kk < 8; ++kk) {
      if (kk < A || kk > A + 3) wSk[rloc * 136 + us0 + 16 * kk] = 0;
    }
  }

  // ---- one-tile-ahead prefetch registers (wave-private) -------------------
  float4 kpf[4], rkpf[8], vpf[4], rvpf[8];

  auto issueKRK = [&](const int j0, const int i0) {
#pragma unroll
    for (int i2 = 0; i2 < 4; ++i2) {
      const int idx = t + (i2 << 8);
      kpf[i2] = *(const float4*)(k + ((size_t)(bh * SS + j0 + (idx >> 4))) * DD + (idx & 15) * 4);
    }
    const int pLo = j0 - i0 - 63 + 512;
#pragma unroll
    for (int i2 = 0; i2 < 8; ++i2) {
      const int idx = t + (i2 << 8);
      int pp = pLo + (idx >> 4);
      pp = pp < 0 ? 0 : (pp > 512 ? 512 : pp);
      rkpf[i2] = *(const float4*)(RK + (size_t)pp * DD + (idx & 15) * 4);
    }
    __builtin_amdgcn_sched_barrier(0);  // pin issue here (r7: sunk without)
  };
  auto issueVRV = [&](const int j0, const int i0) {
#pragma unroll
    for (int i2 = 0; i2 < 4; ++i2) {
      const int idx = t + (i2 << 8);
      vpf[i2] = *(const float4*)(v + ((size_t)(bh * SS + j0 + (idx >> 4))) * DD + (idx & 15) * 4);
    }
    const int pLo = j0 - i0 - 63 + 512;
#pragma unroll
    for (int i2 = 0; i2 < 8; ++i2) {
      const int idx = t + (i2 << 8);
      int pp = pLo + (idx >> 4);
      pp = pp < 0 ? 0 : (pp > 512 ? 512 : pp);
      rvpf[i2] = *(const float4*)(RV + (size_t)pp * DD + (idx & 15) * 4);
    }
    __builtin_amdgcn_sched_barrier(0);
  };

  // phase A: convert ALL prefetched regs -> LDS (K/RK + vT/rvT)
  auto stageAll = [&]() {
#pragma unroll
    for (int i2 = 0; i2 < 4; ++i2) {
      const int idx = t + (i2 << 8);
      const int row = idx >> 4, c4 = (idx & 15) * 4;
      const float xs[4] = {kpf[i2].x, kpf[i2].y, kpf[i2].z, kpf[i2].w};
      sx4 h, l;
#pragma unroll
      for (int e = 0; e < 4; ++e) {
        const unsigned short hb = f2bf(xs[e]);
        h[e] = (short)hb;
        l[e] = (short)f2bf(xs[e] - bf2f(hb));
      }
      *(sx4*)&sKh[row * 72 + c4] = h;
      *(sx4*)&sKl[row * 72 + c4] = l;
    }
#pragma unroll
    for (int i2 = 0; i2 < 8; ++i2) {
      const int idx = t + (i2 << 8);
      const int u = idx >> 4, c4 = (idx & 15) * 4;
      sx4 h;
      h[0] = (short)f2bf(rkpf[i2].x); h[1] = (short)f2bf(rkpf[i2].y);
      h[2] = (short)f2bf(rkpf[i2].z); h[3] = (short)f2bf(rkpf[i2].w);
      *(sx4*)&sRh[u * 72 + c4] = h;
    }
#pragma unroll
    for (int i2 = 0; i2 < 4; ++i2) {
      const int idx = t + (i2 << 8);
      const int jj = idx >> 4, d4 = (idx & 15) * 4;
      vT[(d4 + 0) * 74 + jj] = (short)f2bf(vpf[i2].x);
      vT[(d4 + 1) * 74 + jj] = (short)f2bf(vpf[i2].y);
      vT[(d4 + 2) * 74 + jj] = (short)f2bf(vpf[i2].z);
      vT[(d4 + 3) * 74 + jj] = (short)f2bf(vpf[i2].w);
    }
#pragma unroll
    for (int i2 = 0; i2 < 8; ++i2) {
      const int idx = t + (i2 << 8);
      const int u = idx >> 4, d4 = (idx & 15) * 4;
      rvT[(d4 + 0) * 138 + u] = (short)f2bf(rvpf[i2].x);
      rvT[(d4 + 1) * 138 + u] = (short)f2bf(rvpf[i2].y);
      rvT[(d4 + 2) * 138 + u] = (short)f2bf(rvpf[i2].z);
      rvT[(d4 + 3) * 138 + u] = (short)f2bf(rvpf[i2].w);
    }
  };

  // prologue: issue half-0 tile-0 loads; latency soaks under zero + Q phases
  issueKRK(0, p << 6);
  issueVRV(0, p << 6);

  for (int half = 0; half < 2; ++half) {
    const int it = half ? 15 - p : p;
    const int i0 = it << 6;

    // zero the fully-masked upper W columns (wave-per-row, contiguous)
    {
      float4 z; z.x = z.y = z.z = z.w = 0.f;
      for (int r = mt; r < 64; r += 4) {
        float* Wrow = W + ((size_t)(bh * SS + i0 + r)) * SS;
        for (int j = (it + 1) * 64 + lane * 4; j < SS; j += 256)
          *(float4*)(Wrow + j) = z;
      }
    }

    // Q fragments (hi/lo split) in registers for this stripe
    sx8 aQh[2], aQl[2];
    {
      const float* qrow = q + ((size_t)(bh * SS + i0 + mt * 16 + lc)) * DD;
#pragma unroll
      for (int ks = 0; ks < 2; ++ks) {
        const int koff = ks * 32 + quad * 8;
        const float4 x0 = *(const float4*)(qrow + koff);
        const float4 x1 = *(const float4*)(qrow + koff + 4);
        const float xs[8] = {x0.x, x0.y, x0.z, x0.w, x1.x, x1.y, x1.z, x1.w};
#pragma unroll
        for (int e = 0; e < 8; ++e) {
          const unsigned short hb = f2bf(xs[e]);
          aQh[ks][e] = (short)hb;
          aQl[ks][e] = (short)f2bf(xs[e] - bf2f(hb));
        }
      }
    }

    const fx4 zz = {0.f, 0.f, 0.f, 0.f};
    float sAcc[4] = {0.f, 0.f, 0.f, 0.f};
    fx4 accO[4] = {zz, zz, zz, zz};

    for (int jt = 0; jt <= it; ++jt) {
      const int j0 = jt * 64;
      if (jt | half) BAR_LGKM();  // prev tile's PV/logits LDS reads done
      stageAll();
      // issue NEXT tile's loads: fly across the lgkm barriers for a full tile
      if (jt < it) { issueKRK(j0 + 64, i0); issueVRV(j0 + 64, i0); }
      else if (half == 0) { issueKRK(0, (15 - p) << 6); issueVRV(0, (15 - p) << 6); }
      BAR_LGKM();  // staged K/RK/vT/rvT visible block-wide

      fx4 accS1[4] = {zz, zz, zz, zz};
      fx4 accS2[5] = {zz, zz, zz, zz, zz};
#pragma unroll
      for (int ks = 0; ks < 2; ++ks) {
        const int koff = ks * 32 + quad * 8;
#pragma unroll
        for (int nt = 0; nt < 4; ++nt) {
          const sx8 bKh = *(const sx8*)&sKh[(nt * 16 + lc) * 72 + koff];
          const sx8 bKl = *(const sx8*)&sKl[(nt * 16 + lc) * 72 + koff];
          accS1[nt] = __builtin_amdgcn_mfma_f32_16x16x32_bf16(aQh[ks], bKh, accS1[nt], 0, 0, 0);
          accS1[nt] = __builtin_amdgcn_mfma_f32_16x16x32_bf16(aQl[ks], bKh, accS1[nt], 0, 0, 0);
          accS1[nt] = __builtin_amdgcn_mfma_f32_16x16x32_bf16(aQh[ks], bKl, accS1[nt], 0, 0, 0);
        }
#pragma unroll
        for (int s = 0; s < 5; ++s) {
          const sx8 bR = *(const sx8*)&sRh[((3 - mt + s) * 16 + lc) * 72 + koff];
          accS2[s] = __builtin_amdgcn_mfma_f32_16x16x32_bf16(aQh[ks], bR, accS2[s], 0, 0, 0);
        }
      }
      BAR_LGKM();  // logits reads done -> sKh region (wA alias) is free

      // ---- sync-free back half: epilogue + direct W-store + PV -----------
      // w~ = exp(logit); W written straight from registers (scattered,
      // r6-proven equal); wA/wSk writes are WAVE-PRIVATE (own 16-row slice).
#pragma unroll
      for (int nt = 0; nt < 4; ++nt) {
#pragma unroll
        for (int e = 0; e < 4; ++e) {
          const int rr = quad * 4 + e;
          const int du = 63 + lc - rr;
          const int srcLane = (lane & 48) | (du & 15);
          const float g0 = __shfl(accS2[nt][e], srcLane, 64);
          const float g1 = __shfl(accS2[nt + 1][e], srcLane, 64);
          const float val = accS1[nt][e] + (du < 64 ? g0 : g1);
          const int col = j0 + nt * 16 + lc;
          const int rowg = i0 + mt * 16 + rr;
          const float w = (col <= rowg) ? __expf(val) : 0.f;
          W[((size_t)(bh * SS + rowg)) * SS + col] = w;
          sAcc[e] += w;
          const unsigned short h = f2bf(w);
          wA[(mt * 16 + rr) * 72 + nt * 16 + lc] = (short)h;
          wSk[(mt * 16 + rr) * 136 + du + 16 * (nt - mt)] = (short)h;
        }
      }
      // wave-local ordering: own wA/wSk writes complete before own PV reads
      asm volatile("s_waitcnt lgkmcnt(0)" ::: "memory");
      __builtin_amdgcn_sched_barrier(0);

      // O += w~ @ v   (K = 64 over j)
#pragma unroll
      for (int ks = 0; ks < 2; ++ks) {
        const int koff = ks * 32 + quad * 8;
        const sx8 aW = *(const sx8*)&wA[(mt * 16 + lc) * 72 + koff];
#pragma unroll
        for (int nt = 0; nt < 4; ++nt) {
          const sx8 bV = *(const sx8*)&vT[(nt * 16 + lc) * 74 + koff];
          accO[nt] = __builtin_amdgcn_mfma_f32_16x16x32_bf16(aW, bV, accO[nt], 0, 0, 0);
        }
      }
      // O += w~skew @ RVstaged   (K = 128 over u)
#pragma unroll
      for (int ks = 0; ks < 4; ++ks) {
        const int koff = ks * 32 + quad * 8;
        const sx8 aS = *(const sx8*)&wSk[(mt * 16 + lc) * 136 + koff];
#pragma unroll
        for (int nt = 0; nt < 4; ++nt) {
          const sx8 bR = *(const sx8*)&rvT[(nt * 16 + lc) * 138 + koff];
          accO[nt] = __builtin_amdgcn_mfma_f32_16x16x32_bf16(aS, bR, accO[nt], 0, 0, 0);
        }
      }
    }

    // ---- stripe tail (cold path: FULL barriers — vmcnt drain needed) -----
    __syncthreads();  // all W-stores retired & visible; LDS quiesced

    // reduce row-sum partials across the 16 lanes of each quad
#pragma unroll
    for (int off = 1; off <= 8; off <<= 1) {
#pragma unroll
      for (int e = 0; e < 4; ++e) sAcc[e] += __shfl_xor(sAcc[e], off, 64);
    }
    float rI[4];
#pragma unroll
    for (int e = 0; e < 4; ++e) rI[e] = 1.f / sAcc[e];

    // publish row inverses to LDS (vT region; all PV reads drained)
    if (lc == 0) {
#pragma unroll
      for (int e = 0; e < 4; ++e) rowInvLds[mt * 16 + quad * 4 + e] = rI[e];
    }

    // write O scaled by 1/rowSum (registers; no LDS dependency)
#pragma unroll
    for (int nt = 0; nt < 4; ++nt) {
#pragma unroll
      for (int e = 0; e < 4; ++e) {
        O[((size_t)(bh * SS + i0 + mt * 16 + quad * 4 + e)) * DD + nt * 16 + lc] =
            accO[nt][e] * rI[e];
      }
    }

    __syncthreads();  // rowInvLds visible
    __threadfence_block();
    // normalize this block's 64 W-rows (wave-per-row, contiguous)
    {
      const int ncol = i0 + 64;
      for (int r = mt; r < 64; r += 4) {
        const float inv = rowInvLds[r];
        float* __restrict__ Wrow = W + ((size_t)(bh * SS + i0 + r)) * SS;
        for (int j = lane * 4; j < ncol; j += 256) {
          float4 x = *(const float4*)(Wrow + j);
          x.x *= inv; x.y *= inv; x.z *= inv; x.w *= inv;
          *(float4*)(Wrow + j) = x;
        }
      }
    }
    __syncthreads();  // tail LDS reads done before next half overwrites
  }
}

extern "C" void kernel_launch(void* const* d_in, const int* in_sizes, int n_in,
                              void* d_out, int out_size, void* d_ws, size_t ws_size,
                              hipStream_t stream) {
  const float* q = (const float*)d_in[0];
  const float* k = (const float*)d_in[1];
  const float* v = (const float*)d_in[2];
  const float* RK = (const float*)d_in[3];  // (1025,64); causal => rows 0..512
  const float* RV = (const float*)d_in[4];

  float* O = (float*)d_out;                         // (B,H,S,D)
  float* W = (float*)d_out + (size_t)BH * SS * DD;  // (B,H,S,S)

  k_fused<<<dim3(8, BH), 256, 0, stream>>>(q, k, v, RK, RV, W, O);
}